// Round 1
// baseline (278.578 us; speedup 1.0000x reference)
//
#include <hip/hip_runtime.h>

typedef short s16x8 __attribute__((ext_vector_type(8)));
typedef float f32x4 __attribute__((ext_vector_type(4)));
typedef unsigned short u16;

#define MFMA_BF16(a, b, c) __builtin_amdgcn_mfma_f32_16x16x32_bf16((a), (b), (c), 0, 0, 0)

__device__ __forceinline__ u16 f2bf(float f) {
  unsigned u = __builtin_bit_cast(unsigned, f);
  unsigned r = (u + 0x7FFFu + ((u >> 16) & 1u)) >> 16;
  return (u16)r;
}

// ---------------- fp32 -> bf16 elementwise (x) ----------------
__global__ __launch_bounds__(256) void cvt_bf16(const float* __restrict__ in,
                                                u16* __restrict__ out, int n4) {
  int i = blockIdx.x * 256 + threadIdx.x;
  if (i < n4) {
    float4 v = reinterpret_cast<const float4*>(in)[i];
    ushort4 o;
    o.x = f2bf(v.x); o.y = f2bf(v.y); o.z = f2bf(v.z); o.w = f2bf(v.w);
    reinterpret_cast<ushort4*>(out)[i] = o;
  }
}

// ---------------- fp32 [1024][1024] -> bf16 transpose Wt[n][k] = W[k][n] ----------------
__global__ __launch_bounds__(256) void transp_bf16(const float* __restrict__ W,
                                                   u16* __restrict__ Wt) {
  __shared__ float tile[64][65];
  int n0 = blockIdx.x * 64, k0 = blockIdx.y * 64;
  int t = threadIdx.x;
#pragma unroll
  for (int i = 0; i < 16; i++) {
    int idx = t + i * 256;
    int r = idx >> 6, c = idx & 63;
    tile[r][c] = W[(k0 + r) * 1024 + (n0 + c)];
  }
  __syncthreads();
#pragma unroll
  for (int i = 0; i < 16; i++) {
    int idx = t + i * 256;
    int r = idx >> 6, c = idx & 63;
    Wt[(n0 + r) * 1024 + (k0 + c)] = f2bf(tile[c][r]);
  }
}

// ---------------- generic bf16 GEMM: C[M=grid.y*128][N=grid.x*128] = A[M][1024] @ Bt[N][1024]^T
// MODE 0: out bf16 [B=2][H=16][S=2048][64]   (Q, K)
// MODE 1: out bf16 [B=2][H=16][64][S=2048]   (V transposed)
// MODE 2: out fp32 [M][1024] = acc + bias[n] (final projection)
template <int MODE>
__global__ __launch_bounds__(256) void gemm_bf16(const u16* __restrict__ A,
                                                 const u16* __restrict__ Bt,
                                                 const float* __restrict__ bias,
                                                 void* __restrict__ outp) {
  constexpr int K = 1024;
  __shared__ __align__(16) u16 At[128 * 40];
  __shared__ __align__(16) u16 Bs[128 * 40];
  int t = threadIdx.x;
  int m0 = blockIdx.y * 128, n0 = blockIdx.x * 128;
  int w = t >> 6, lane = t & 63;
  int wm = (w >> 1) * 64, wn = (w & 1) * 64;
  int g = lane >> 4, ql = lane & 15;

  f32x4 acc[4][4];
#pragma unroll
  for (int i = 0; i < 4; i++)
#pragma unroll
    for (int j = 0; j < 4; j++) acc[i][j] = f32x4{0.f, 0.f, 0.f, 0.f};

  int srow = t >> 1, scol = (t & 1) * 16;
  const u16* Ag = A + (m0 + srow) * K + scol;
  const u16* Bg = Bt + (n0 + srow) * K + scol;

  for (int k0 = 0; k0 < K; k0 += 32) {
    __syncthreads();
    s16x8 a0 = *reinterpret_cast<const s16x8*>(Ag + k0);
    s16x8 a1 = *reinterpret_cast<const s16x8*>(Ag + k0 + 8);
    s16x8 b0 = *reinterpret_cast<const s16x8*>(Bg + k0);
    s16x8 b1 = *reinterpret_cast<const s16x8*>(Bg + k0 + 8);
    *reinterpret_cast<s16x8*>(At + srow * 40 + scol) = a0;
    *reinterpret_cast<s16x8*>(At + srow * 40 + scol + 8) = a1;
    *reinterpret_cast<s16x8*>(Bs + srow * 40 + scol) = b0;
    *reinterpret_cast<s16x8*>(Bs + srow * 40 + scol + 8) = b1;
    __syncthreads();

    s16x8 af[4], bfr[4];
#pragma unroll
    for (int fm = 0; fm < 4; fm++)
      af[fm] = *reinterpret_cast<const s16x8*>(At + (wm + fm * 16 + ql) * 40 + g * 8);
#pragma unroll
    for (int fn = 0; fn < 4; fn++)
      bfr[fn] = *reinterpret_cast<const s16x8*>(Bs + (wn + fn * 16 + ql) * 40 + g * 8);
#pragma unroll
    for (int fm = 0; fm < 4; fm++)
#pragma unroll
      for (int fn = 0; fn < 4; fn++)
        acc[fm][fn] = MFMA_BF16(af[fm], bfr[fn], acc[fm][fn]);
  }

  // epilogue: element (m, n), C-layout col=lane&15, row=(lane>>4)*4+j
#pragma unroll
  for (int fm = 0; fm < 4; fm++)
#pragma unroll
    for (int fn = 0; fn < 4; fn++)
#pragma unroll
      for (int j = 0; j < 4; j++) {
        int m = m0 + wm + fm * 16 + g * 4 + j;
        int n = n0 + wn + fn * 16 + ql;
        float v = acc[fm][fn][j];
        if (MODE == 0) {
          u16* o = (u16*)outp;
          o[(((m >> 11) * 16 + (n >> 6)) * 2048 + (m & 2047)) * 64 + (n & 63)] = f2bf(v);
        } else if (MODE == 1) {
          u16* o = (u16*)outp;
          o[(((m >> 11) * 16 + (n >> 6)) * 64 + (n & 63)) * 2048 + (m & 2047)] = f2bf(v);
        } else {
          ((float*)outp)[m * 1024 + n] = v + bias[n];
        }
      }
}

// ---------------- flash attention: 1 wave per 16-row Q tile ----------------
// Q,K: [BH=32][S=2048][64] bf16; Vt: [BH][64][2048] bf16; Ctx: [4096][1024] bf16
__global__ __launch_bounds__(256) void attn_kernel(const u16* __restrict__ Q,
                                                   const u16* __restrict__ Kb,
                                                   const u16* __restrict__ Vt,
                                                   u16* __restrict__ Ctx) {
  __shared__ __align__(16) u16 P[4 * 16 * 40];
  int t = threadIdx.x, w = t >> 6, lane = t & 63;
  int g = lane >> 4, ql = lane & 15;
  int bh = blockIdx.x >> 5, qg = blockIdx.x & 31;
  int qt = w * 32 + qg;  // spread work so each block's waves have equal causal length
  int q0 = qt * 16;
  u16* Pw = P + w * 640;

  const u16* Qp = Q + (bh * 2048 + q0) * 64;
  const u16* Kp = Kb + bh * 2048 * 64;
  const u16* Vp = Vt + bh * 64 * 2048;

  s16x8 aq0 = *reinterpret_cast<const s16x8*>(Qp + ql * 64 + g * 8);
  s16x8 aq1 = *reinterpret_cast<const s16x8*>(Qp + ql * 64 + 32 + g * 8);

  f32x4 o[4];
#pragma unroll
  for (int d = 0; d < 4; d++) o[d] = f32x4{0.f, 0.f, 0.f, 0.f};
  float mj[4] = {-INFINITY, -INFINITY, -INFINITY, -INFINITY};
  float lj[4] = {0.f, 0.f, 0.f, 0.f};
  int qrow = q0 + g * 4;  // + j

  int nkt = ((q0 + 15) >> 5) + 1;
  for (int kt = 0; kt < nkt; ++kt) {
    int kb = kt << 5;
    const u16* kp = Kp + (kb + ql) * 64 + g * 8;
    s16x8 k00 = *reinterpret_cast<const s16x8*>(kp);
    s16x8 k01 = *reinterpret_cast<const s16x8*>(kp + 32);
    s16x8 k10 = *reinterpret_cast<const s16x8*>(kp + 16 * 64);
    s16x8 k11 = *reinterpret_cast<const s16x8*>(kp + 16 * 64 + 32);

    f32x4 s0 = f32x4{0.f, 0.f, 0.f, 0.f};
    f32x4 s1 = f32x4{0.f, 0.f, 0.f, 0.f};
    s0 = MFMA_BF16(aq0, k00, s0);
    s0 = MFMA_BF16(aq1, k01, s0);
    s1 = MFMA_BF16(aq0, k10, s1);
    s1 = MFMA_BF16(aq1, k11, s1);

#pragma unroll
    for (int j = 0; j < 3 + 1; j++) {
      float x0 = (kb + ql <= qrow + j) ? s0[j] * 0.125f : -INFINITY;
      float x1 = (kb + 16 + ql <= qrow + j) ? s1[j] * 0.125f : -INFINITY;
      float r = fmaxf(x0, x1);
#pragma unroll
      for (int msk = 1; msk < 16; msk <<= 1) r = fmaxf(r, __shfl_xor(r, msk));
      float nm = fmaxf(mj[j], r);
      x0 = __expf(x0 - nm);
      x1 = __expf(x1 - nm);
      float s = x0 + x1;
#pragma unroll
      for (int msk = 1; msk < 16; msk <<= 1) s += __shfl_xor(s, msk);
      float alpha = __expf(mj[j] - nm);
      lj[j] = lj[j] * alpha + s;
      mj[j] = nm;
#pragma unroll
      for (int d = 0; d < 4; d++) o[d][j] *= alpha;
      Pw[(g * 4 + j) * 40 + ql] = f2bf(x0);
      Pw[(g * 4 + j) * 40 + 16 + ql] = f2bf(x1);
    }
    asm volatile("s_waitcnt lgkmcnt(0)" ::: "memory");
    __builtin_amdgcn_sched_barrier(0);

    s16x8 ap = *reinterpret_cast<const s16x8*>(Pw + ql * 40 + g * 8);
    const u16* vp = Vp + ql * 2048 + kb + g * 8;
#pragma unroll
    for (int d = 0; d < 4; d++) {
      s16x8 bv = *reinterpret_cast<const s16x8*>(vp + d * 16 * 2048);
      o[d] = MFMA_BF16(ap, bv, o[d]);
    }
  }

  int b = bh >> 4, h = bh & 15;
  int orow = b * 2048 + q0 + g * 4;
#pragma unroll
  for (int j = 0; j < 4; j++) {
    float inv = 1.0f / lj[j];
#pragma unroll
    for (int d = 0; d < 4; d++)
      Ctx[(orow + j) * 1024 + h * 64 + d * 16 + ql] = f2bf(o[d][j] * inv);
  }
}

extern "C" void kernel_launch(void* const* d_in, const int* in_sizes, int n_in,
                              void* d_out, int out_size, void* d_ws, size_t ws_size,
                              hipStream_t stream) {
  const float* x = (const float*)d_in[0];
  const float* wq = (const float*)d_in[1];
  const float* wk = (const float*)d_in[2];
  const float* wv = (const float*)d_in[3];
  const float* wo = (const float*)d_in[4];
  const float* bo = (const float*)d_in[5];

  char* ws = (char*)d_ws;
  const size_t MB = 1 << 20;
  u16* xb  = (u16*)(ws + 0 * MB);    // 8 MB  : x bf16 [4096][1024]
  u16* wqt = (u16*)(ws + 8 * MB);    // 2 MB  : wq^T bf16
  u16* wkt = (u16*)(ws + 10 * MB);
  u16* wvt = (u16*)(ws + 12 * MB);
  u16* wot = (u16*)(ws + 14 * MB);
  u16* qb  = (u16*)(ws + 16 * MB);   // 8 MB  : Q [32][2048][64]
  u16* kb  = (u16*)(ws + 24 * MB);   // 8 MB  : K [32][2048][64]
  u16* vtb = (u16*)(ws + 32 * MB);   // 8 MB  : V^T [32][64][2048]
  u16* ctx = (u16*)(ws + 40 * MB);   // 8 MB  : ctx [4096][1024]

  cvt_bf16<<<4096, 256, 0, stream>>>(x, xb, 1048576);
  transp_bf16<<<dim3(16, 16), 256, 0, stream>>>(wq, wqt);
  transp_bf16<<<dim3(16, 16), 256, 0, stream>>>(wk, wkt);
  transp_bf16<<<dim3(16, 16), 256, 0, stream>>>(wv, wvt);
  transp_bf16<<<dim3(16, 16), 256, 0, stream>>>(wo, wot);

  gemm_bf16<0><<<dim3(8, 32), 256, 0, stream>>>(xb, wqt, nullptr, qb);
  gemm_bf16<0><<<dim3(8, 32), 256, 0, stream>>>(xb, wkt, nullptr, kb);
  gemm_bf16<1><<<dim3(8, 32), 256, 0, stream>>>(xb, wvt, nullptr, vtb);

  attn_kernel<<<1024, 256, 0, stream>>>(qb, kb, vtb, ctx);

  gemm_bf16<2><<<dim3(8, 32), 256, 0, stream>>>(ctx, wot, bo, d_out);
}

// Round 4
// 204.218 us; speedup vs baseline: 1.3641x; 1.3641x over previous
//
#include <hip/hip_runtime.h>

typedef short s16x8 __attribute__((ext_vector_type(8)));
typedef float f32x4 __attribute__((ext_vector_type(4)));
typedef float f32x16 __attribute__((ext_vector_type(16)));
typedef unsigned int u32;
typedef u32 u32x2 __attribute__((ext_vector_type(2)));
typedef u32 u32x4 __attribute__((ext_vector_type(4)));
typedef unsigned short u16;

#define MFMA16(a, b, c) __builtin_amdgcn_mfma_f32_16x16x32_bf16((a), (b), (c), 0, 0, 0)
#define MFMA32(a, b, c) __builtin_amdgcn_mfma_f32_32x32x16_bf16((a), (b), (c), 0, 0, 0)

__device__ __forceinline__ u16 f2bf(float f) {
  unsigned u = __builtin_bit_cast(unsigned, f);
  unsigned r = (u + 0x7FFFu + ((u >> 16) & 1u)) >> 16;
  return (u16)r;
}

__device__ __forceinline__ u32 pack2bf(float lo, float hi) {
  return (u32)f2bf(lo) | ((u32)f2bf(hi) << 16);
}

__device__ __forceinline__ u32 sx32(u32 v) {
  return (u32)__shfl_xor((int)v, 32);
}

// ---------------- fp32 -> bf16 elementwise (x) ----------------
__global__ __launch_bounds__(256) void cvt_bf16(const float* __restrict__ in,
                                                u16* __restrict__ out, int n4) {
  int i = blockIdx.x * 256 + threadIdx.x;
  if (i < n4) {
    float4 v = reinterpret_cast<const float4*>(in)[i];
    ushort4 o;
    o.x = f2bf(v.x); o.y = f2bf(v.y); o.z = f2bf(v.z); o.w = f2bf(v.w);
    reinterpret_cast<ushort4*>(out)[i] = o;
  }
}

// ---------------- fp32 [1024][1024] -> bf16 transpose Wt[n][k] = W[k][n] ----------------
__global__ __launch_bounds__(256) void transp_bf16(const float* __restrict__ W,
                                                   u16* __restrict__ Wt) {
  __shared__ float tile[64][65];
  int n0 = blockIdx.x * 64, k0 = blockIdx.y * 64;
  int t = threadIdx.x;
#pragma unroll
  for (int i = 0; i < 16; i++) {
    int idx = t + i * 256;
    int r = idx >> 6, c = idx & 63;
    tile[r][c] = W[(k0 + r) * 1024 + (n0 + c)];
  }
  __syncthreads();
#pragma unroll
  for (int i = 0; i < 16; i++) {
    int idx = t + i * 256;
    int r = idx >> 6, c = idx & 63;
    Wt[(n0 + r) * 1024 + (k0 + c)] = f2bf(tile[c][r]);
  }
}

// ---------------- generic bf16 GEMM: C[M][N] = scale * (A[M][1024] @ Bt[N][1024]^T)
// MODE 0: out bf16 [B=2][H=16][S=2048][64]   (Q with scale, K with scale=1)
// MODE 1: out bf16 [B=2][H=16][64][S=2048]   (V transposed)
// MODE 2: out fp32 [M][1024] = acc + bias[n] (final projection)
template <int MODE>
__global__ __launch_bounds__(256) void gemm_bf16(const u16* __restrict__ A,
                                                 const u16* __restrict__ Bt,
                                                 const float* __restrict__ bias,
                                                 void* __restrict__ outp, float scale) {
  constexpr int K = 1024;
  __shared__ __align__(16) u16 At[128 * 40];
  __shared__ __align__(16) u16 Bs[128 * 40];
  int t = threadIdx.x;
  int m0 = blockIdx.y * 128, n0 = blockIdx.x * 128;
  int w = t >> 6, lane = t & 63;
  int wm = (w >> 1) * 64, wn = (w & 1) * 64;
  int g = lane >> 4, ql = lane & 15;

  f32x4 acc[4][4];
#pragma unroll
  for (int i = 0; i < 4; i++)
#pragma unroll
    for (int j = 0; j < 4; j++) acc[i][j] = f32x4{0.f, 0.f, 0.f, 0.f};

  int srow = t >> 1, scol = (t & 1) * 16;
  const u16* Ag = A + (m0 + srow) * K + scol;
  const u16* Bg = Bt + (n0 + srow) * K + scol;

  for (int k0 = 0; k0 < K; k0 += 32) {
    __syncthreads();
    s16x8 a0 = *reinterpret_cast<const s16x8*>(Ag + k0);
    s16x8 a1 = *reinterpret_cast<const s16x8*>(Ag + k0 + 8);
    s16x8 b0 = *reinterpret_cast<const s16x8*>(Bg + k0);
    s16x8 b1 = *reinterpret_cast<const s16x8*>(Bg + k0 + 8);
    *reinterpret_cast<s16x8*>(At + srow * 40 + scol) = a0;
    *reinterpret_cast<s16x8*>(At + srow * 40 + scol + 8) = a1;
    *reinterpret_cast<s16x8*>(Bs + srow * 40 + scol) = b0;
    *reinterpret_cast<s16x8*>(Bs + srow * 40 + scol + 8) = b1;
    __syncthreads();

    s16x8 af[4], bfr[4];
#pragma unroll
    for (int fm = 0; fm < 4; fm++)
      af[fm] = *reinterpret_cast<const s16x8*>(At + (wm + fm * 16 + ql) * 40 + g * 8);
#pragma unroll
    for (int fn = 0; fn < 4; fn++)
      bfr[fn] = *reinterpret_cast<const s16x8*>(Bs + (wn + fn * 16 + ql) * 40 + g * 8);
#pragma unroll
    for (int fm = 0; fm < 4; fm++)
#pragma unroll
      for (int fn = 0; fn < 4; fn++)
        acc[fm][fn] = MFMA16(af[fm], bfr[fn], acc[fm][fn]);
  }

  // epilogue: element (m, n), C-layout col=lane&15, row=(lane>>4)*4+j
#pragma unroll
  for (int fm = 0; fm < 4; fm++)
#pragma unroll
    for (int fn = 0; fn < 4; fn++)
#pragma unroll
      for (int j = 0; j < 4; j++) {
        int m = m0 + wm + fm * 16 + g * 4 + j;
        int n = n0 + wn + fn * 16 + ql;
        float v = acc[fm][fn][j] * scale;
        if (MODE == 0) {
          u16* o = (u16*)outp;
          o[(((m >> 11) * 16 + (n >> 6)) * 2048 + (m & 2047)) * 64 + (n & 63)] = f2bf(v);
        } else if (MODE == 1) {
          u16* o = (u16*)outp;
          o[(((m >> 11) * 16 + (n >> 6)) * 64 + (n & 63)) * 2048 + (m & 2047)] = f2bf(v);
        } else {
          ((float*)outp)[m * 1024 + n] = v + bias[n];
        }
      }
}

// ---------------- flash attention, swapped-operand 32x32 structure ----------------
// Q,K: [BH=32][S=2048][64] bf16 (Q pre-scaled by 0.125*log2e); Vt: [BH][64][2048] bf16
// Ctx: [4096][1024] bf16.
// Per wave: 32 q rows. S^T = K @ Q^T via mfma32 (lane holds 16 keys for one q col).
// Softmax fully in-register (exp2 domain); cross-lane ops via __shfl_xor(32) only.
__global__ __launch_bounds__(256) void attn_kernel(const u16* __restrict__ Q,
                                                   const u16* __restrict__ Kb,
                                                   const u16* __restrict__ Vt,
                                                   u16* __restrict__ Ctx) {
  __shared__ __align__(16) u16 tl[4][32 * 68];
  int t = threadIdx.x, w = t >> 6, l = t & 63;
  int lq = l & 31, h = l >> 5;

  // XCD pinning: head % 8 == blockIdx % 8 so each XCD's L2 holds 4 heads' K/V.
  int B = blockIdx.x;
  int xcd = B & 7, j = B >> 3;
  int head = (j & 3) * 8 + xcd;   // 0..31
  int pos = j >> 2;               // 0..15
  // causal load balance: block's 4 waves get q-tiles summing to a constant
  int qt = (w == 0) ? pos : (w == 1) ? 63 - pos : (w == 2) ? 31 - pos : 32 + pos;
  int q0 = qt * 32;

  const u16* Qp = Q + (head * 2048 + q0) * 64;
  const u16* Kp = Kb + head * 2048 * 64;
  const u16* Vp = Vt + head * 64 * 2048;

  // Q fragments (B-operand: Q^T[d][q], lane holds q=lq, d = f*16 + h*8 + j)
  s16x8 qf[4];
#pragma unroll
  for (int f = 0; f < 4; f++)
    qf[f] = *reinterpret_cast<const s16x8*>(Qp + lq * 64 + f * 16 + h * 8);

  f32x16 oacc[2];
#pragma unroll
  for (int dt = 0; dt < 2; dt++)
#pragma unroll
    for (int r = 0; r < 16; r++) oacc[dt][r] = 0.f;

  float mrun = -INFINITY, lrun = 0.f;
  int q = q0 + lq;
  int nt = qt + 1;

  // preload K tile 0 (A-operand: K[key][d], lane holds key=lq, d = f*16 + h*8 + j)
  s16x8 kc[4];
#pragma unroll
  for (int f = 0; f < 4; f++)
    kc[f] = *reinterpret_cast<const s16x8*>(Kp + lq * 64 + f * 16 + h * 8);

  for (int kt = 0; kt < nt; kt++) {
    int kb = kt * 32;

    // V fragments for this tile (A-operand of PV: V^T[d][key])
    s16x8 vf[2][2];
#pragma unroll
    for (int dt = 0; dt < 2; dt++)
#pragma unroll
      for (int kh = 0; kh < 2; kh++)
        vf[dt][kh] = *reinterpret_cast<const s16x8*>(
            Vp + (dt * 32 + lq) * 2048 + kb + kh * 16 + h * 8);

    // S^T tile: rows=key (reg-mapped), col=q
    f32x16 s;
#pragma unroll
    for (int r = 0; r < 16; r++) s[r] = 0.f;
#pragma unroll
    for (int f = 0; f < 4; f++) s = MFMA32(kc[f], qf[f], s);

    // prefetch next K tile (hides under softmax+PV)
    if (kt + 1 < nt) {
#pragma unroll
      for (int f = 0; f < 4; f++)
        kc[f] = *reinterpret_cast<const s16x8*>(
            Kp + (kb + 32 + lq) * 64 + f * 16 + h * 8);
    }

    float p[16];
    if (kb == q0) {  // diagonal tile: the only masked one
#pragma unroll
      for (int r = 0; r < 16; r++) {
        int key = kb + (r & 3) + 8 * (r >> 2) + 4 * h;
        p[r] = (key <= q) ? s[r] : -INFINITY;
      }
    } else {
#pragma unroll
      for (int r = 0; r < 16; r++) p[r] = s[r];
    }

    // in-register softmax (log2 domain; Q pre-scaled by 0.125*log2e)
    float tm = p[0];
#pragma unroll
    for (int r = 1; r < 16; r++) tm = fmaxf(tm, p[r]);
    tm = fmaxf(tm, __shfl_xor(tm, 32));
    float mnew = fmaxf(mrun, tm);
    float alpha = exp2f(mrun - mnew);
    mrun = mnew;
    float sum = 0.f;
#pragma unroll
    for (int r = 0; r < 16; r++) {
      p[r] = exp2f(p[r] - mnew);
      sum += p[r];
    }
    sum += __shfl_xor(sum, 32);
    lrun = lrun * alpha + sum;
#pragma unroll
    for (int r = 0; r < 16; r++) { oacc[0][r] *= alpha; oacc[1][r] *= alpha; }

    // pack P^T to bf16 B-fragments via shfl_xor(32) exchange.
    // lane(h=0) holds keys {0-3,8-11,16-19,24-27}(+kb), h=1 holds {4-7,...}.
    // Fragment element j needs key kb + kh*16 + h*8 + j.
    u32 pw[2][4];
#pragma unroll
    for (int kh = 0; kh < 2; kh++) {
      u32 w0 = pack2bf(p[kh * 8 + 0], p[kh * 8 + 1]);
      u32 w1 = pack2bf(p[kh * 8 + 2], p[kh * 8 + 3]);
      u32 w2 = pack2bf(p[kh * 8 + 4], p[kh * 8 + 5]);
      u32 w3 = pack2bf(p[kh * 8 + 6], p[kh * 8 + 7]);
      u32 y0 = sx32(w0);
      u32 y1 = sx32(w1);
      u32 y2 = sx32(w2);
      u32 y3 = sx32(w3);
      pw[kh][0] = h ? y2 : w0;  // j=0,1
      pw[kh][1] = h ? y3 : w1;  // j=2,3
      pw[kh][2] = h ? w2 : y0;  // j=4,5
      pw[kh][3] = h ? w3 : y1;  // j=6,7
    }

    // O^T += V^T @ P^T
#pragma unroll
    for (int kh = 0; kh < 2; kh++) {
      s16x8 pf = __builtin_bit_cast(s16x8, u32x4{pw[kh][0], pw[kh][1], pw[kh][2], pw[kh][3]});
      oacc[0] = MFMA32(vf[0][kh], pf, oacc[0]);
      oacc[1] = MFMA32(vf[1][kh], pf, oacc[1]);
    }
  }

  // epilogue: normalize, transpose O^T[d][q] -> [q][d] through LDS, coalesced store
  float invl = 1.0f / lrun;
  u16* myl = tl[w];
#pragma unroll
  for (int dt = 0; dt < 2; dt++)
#pragma unroll
    for (int i = 0; i < 8; i++) {
      int d = ((2 * i) & 3) + 8 * (i >> 1) + 4 * h + dt * 32;
      u32 pkv = pack2bf(oacc[dt][2 * i] * invl, oacc[dt][2 * i + 1] * invl);
      *reinterpret_cast<u32*>(myl + lq * 68 + d) = pkv;
    }

  int b = head >> 4, hh = head & 15;
  int gbase = b * 2048 + q0;
#pragma unroll
  for (int i = 0; i < 8; i++) {
    int chunk = i * 64 + l;
    int row = chunk >> 4, col4 = (chunk & 15) * 4;
    u32x2 v = *reinterpret_cast<const u32x2*>(myl + row * 68 + col4);
    *reinterpret_cast<u32x2*>(Ctx + (gbase + row) * 1024 + hh * 64 + col4) = v;
  }
}

extern "C" void kernel_launch(void* const* d_in, const int* in_sizes, int n_in,
                              void* d_out, int out_size, void* d_ws, size_t ws_size,
                              hipStream_t stream) {
  const float* x = (const float*)d_in[0];
  const float* wq = (const float*)d_in[1];
  const float* wk = (const float*)d_in[2];
  const float* wv = (const float*)d_in[3];
  const float* wo = (const float*)d_in[4];
  const float* bo = (const float*)d_in[5];

  char* ws = (char*)d_ws;
  const size_t MB = 1 << 20;
  u16* xb  = (u16*)(ws + 0 * MB);    // 8 MB  : x bf16 [4096][1024]
  u16* wqt = (u16*)(ws + 8 * MB);    // 2 MB  : wq^T bf16
  u16* wkt = (u16*)(ws + 10 * MB);
  u16* wvt = (u16*)(ws + 12 * MB);
  u16* wot = (u16*)(ws + 14 * MB);
  u16* qb  = (u16*)(ws + 16 * MB);   // 8 MB  : Q [32][2048][64] (pre-scaled)
  u16* kb  = (u16*)(ws + 24 * MB);   // 8 MB  : K [32][2048][64]
  u16* vtb = (u16*)(ws + 32 * MB);   // 8 MB  : V^T [32][64][2048]
  u16* ctx = (u16*)(ws + 40 * MB);   // 8 MB  : ctx [4096][1024]

  cvt_bf16<<<4096, 256, 0, stream>>>(x, xb, 1048576);
  transp_bf16<<<dim3(16, 16), 256, 0, stream>>>(wq, wqt);
  transp_bf16<<<dim3(16, 16), 256, 0, stream>>>(wk, wkt);
  transp_bf16<<<dim3(16, 16), 256, 0, stream>>>(wv, wvt);
  transp_bf16<<<dim3(16, 16), 256, 0, stream>>>(wo, wot);

  const float QSCALE = 0.125f * 1.44269504f;  // 1/sqrt(64) * log2(e)
  gemm_bf16<0><<<dim3(8, 32), 256, 0, stream>>>(xb, wqt, nullptr, qb, QSCALE);
  gemm_bf16<0><<<dim3(8, 32), 256, 0, stream>>>(xb, wkt, nullptr, kb, 1.0f);
  gemm_bf16<1><<<dim3(8, 32), 256, 0, stream>>>(xb, wvt, nullptr, vtb, 1.0f);

  attn_kernel<<<512, 256, 0, stream>>>(qb, kb, vtb, ctx);

  gemm_bf16<2><<<dim3(8, 32), 256, 0, stream>>>(ctx, wot, bo, d_out, 1.0f);
}

// Round 5
// 159.459 us; speedup vs baseline: 1.7470x; 1.2807x over previous
//
#include <hip/hip_runtime.h>

typedef short s16x8 __attribute__((ext_vector_type(8)));
typedef float f32x4 __attribute__((ext_vector_type(4)));
typedef float f32x16 __attribute__((ext_vector_type(16)));
typedef unsigned int u32;
typedef u32 u32x2 __attribute__((ext_vector_type(2)));
typedef u32 u32x4 __attribute__((ext_vector_type(4)));
typedef unsigned short u16;

#define MFMA16(a, b, c) __builtin_amdgcn_mfma_f32_16x16x32_bf16((a), (b), (c), 0, 0, 0)
#define MFMA32(a, b, c) __builtin_amdgcn_mfma_f32_32x32x16_bf16((a), (b), (c), 0, 0, 0)

__device__ __forceinline__ u16 f2bf(float f) {
  unsigned u = __builtin_bit_cast(unsigned, f);
  unsigned r = (u + 0x7FFFu + ((u >> 16) & 1u)) >> 16;
  return (u16)r;
}

__device__ __forceinline__ u32 pack2bf(float lo, float hi) {
  return (u32)f2bf(lo) | ((u32)f2bf(hi) << 16);
}

__device__ __forceinline__ u32 sx32(u32 v) {
  return (u32)__shfl_xor((int)v, 32);
}

// async global->LDS, 16B per lane. LDS dest must be wave-uniform base (HW adds lane*16).
__device__ __forceinline__ void gl_lds16(const u16* g, u16* s) {
  __builtin_amdgcn_global_load_lds(
      (const __attribute__((address_space(1))) void*)g,
      (__attribute__((address_space(3))) void*)s, 16, 0, 0);
}

// ---------------- fp32 -> bf16 elementwise (x) ----------------
__global__ __launch_bounds__(256) void cvt_bf16(const float* __restrict__ in,
                                                u16* __restrict__ out, int n4) {
  int i = blockIdx.x * 256 + threadIdx.x;
  if (i < n4) {
    float4 v = reinterpret_cast<const float4*>(in)[i];
    ushort4 o;
    o.x = f2bf(v.x); o.y = f2bf(v.y); o.z = f2bf(v.z); o.w = f2bf(v.w);
    reinterpret_cast<ushort4*>(out)[i] = o;
  }
}

// ---------------- all 4 weights: fp32 [1024][1024] -> bf16 transpose (one kernel) ----
// z=0..2 -> wqkvt rows z*1024.. (wq scaled by qscale), z=3 -> wot
__global__ __launch_bounds__(256) void transp4(const float* __restrict__ wq,
                                               const float* __restrict__ wk,
                                               const float* __restrict__ wv,
                                               const float* __restrict__ wo,
                                               u16* __restrict__ wqkvt,
                                               u16* __restrict__ wot, float qscale) {
  __shared__ float tile[64][65];
  int z = blockIdx.z;
  const float* W = (z == 0) ? wq : (z == 1) ? wk : (z == 2) ? wv : wo;
  u16* out = (z < 3) ? (wqkvt + z * 1048576) : wot;
  float sc = (z == 0) ? qscale : 1.0f;
  int n0 = blockIdx.x * 64, k0 = blockIdx.y * 64;
  int t = threadIdx.x;
#pragma unroll
  for (int i = 0; i < 16; i++) {
    int idx = t + i * 256;
    int r = idx >> 6, c = idx & 63;
    tile[r][c] = W[(k0 + r) * 1024 + (n0 + c)];
  }
  __syncthreads();
#pragma unroll
  for (int i = 0; i < 16; i++) {
    int idx = t + i * 256;
    int r = idx >> 6, c = idx & 63;
    out[(n0 + r) * 1024 + (k0 + c)] = f2bf(tile[c][r] * sc);
  }
}

// ---------------- 2-phase global_load_lds GEMM: C = A[M][1024] @ Bt[N][1024]^T ------
// MODE 0: fused QKV epilogue. outp = base of {qb, kb, vtb} (each 4M u16).
//         n<1024 -> Q [bh][2048][64]; n<2048 -> K same; else V^T [bh][64][2048].
// MODE 1: fp32 out [M][1024] = acc + bias[n]
template <int MODE>
__global__ __launch_bounds__(256) void gemm2(const u16* __restrict__ A,
                                             const u16* __restrict__ Bt,
                                             const float* __restrict__ bias,
                                             void* __restrict__ outp) {
  constexpr int K = 1024, NT = K / 32;
  __shared__ __align__(16) u16 As[2][128 * 32];
  __shared__ __align__(16) u16 Bs[2][128 * 32];
  int t = threadIdx.x, w = t >> 6, l = t & 63;
  int m0 = blockIdx.y * 128, n0 = blockIdx.x * 128;
  int wm = (w >> 1) * 64, wn = (w & 1) * 64;
  int g = l >> 4, ql = l & 15;

  f32x4 acc[4][4];
#pragma unroll
  for (int i = 0; i < 4; i++)
#pragma unroll
    for (int j = 0; j < 4; j++) acc[i][j] = f32x4{0.f, 0.f, 0.f, 0.f};

  // staging: wave w covers rows [32w, 32w+32) of the 128x32 tile; lane -> (row, col8)
  int lrow = l >> 2, lcol = (l & 3) * 8;
  const u16* Ag0 = A + (m0 + 32 * w + lrow) * K + lcol;
  const u16* Bg0 = Bt + (n0 + 32 * w + lrow) * K + lcol;
  u16* Asw[2] = {&As[0][(32 * w) * 32], &As[1][(32 * w) * 32]};
  u16* Bsw[2] = {&Bs[0][(32 * w) * 32], &Bs[1][(32 * w) * 32]};

#define STAGE(buf, kt)                              \
  do {                                              \
    int k0_ = (kt) * 32;                            \
    gl_lds16(Ag0 + k0_, Asw[buf]);                  \
    gl_lds16(Ag0 + 16 * K + k0_, Asw[buf] + 512);   \
    gl_lds16(Bg0 + k0_, Bsw[buf]);                  \
    gl_lds16(Bg0 + 16 * K + k0_, Bsw[buf] + 512);   \
  } while (0)

#define COMPUTE(buf)                                                              \
  do {                                                                            \
    s16x8 af[4], bv[4];                                                           \
    _Pragma("unroll") for (int fm = 0; fm < 4; fm++)                              \
        af[fm] = *reinterpret_cast<const s16x8*>(                                 \
            &As[buf][(wm + fm * 16 + ql) * 32 + g * 8]);                          \
    _Pragma("unroll") for (int fn = 0; fn < 4; fn++)                              \
        bv[fn] = *reinterpret_cast<const s16x8*>(                                 \
            &Bs[buf][(wn + fn * 16 + ql) * 32 + g * 8]);                          \
    _Pragma("unroll") for (int fm = 0; fm < 4; fm++)                              \
        _Pragma("unroll") for (int fn = 0; fn < 4; fn++)                          \
            acc[fm][fn] = MFMA16(af[fm], bv[fn], acc[fm][fn]);                    \
  } while (0)

  STAGE(0, 0);
  __syncthreads();
  int cur = 0;
  for (int kt = 0; kt < NT - 1; kt++) {
    STAGE(cur ^ 1, kt + 1);
    COMPUTE(cur);
    __syncthreads();
    cur ^= 1;
  }
  COMPUTE(cur);
#undef STAGE
#undef COMPUTE

  // epilogue: element (m, n), C-layout col=lane&15, row=(lane>>4)*4+j
#pragma unroll
  for (int fm = 0; fm < 4; fm++)
#pragma unroll
    for (int fn = 0; fn < 4; fn++)
#pragma unroll
      for (int j = 0; j < 4; j++) {
        int m = m0 + wm + fm * 16 + g * 4 + j;
        int n = n0 + wn + fn * 16 + ql;
        float v = acc[fm][fn][j];
        if (MODE == 0) {
          int proj = n >> 10, nn = n & 1023;
          int bh = (m >> 11) * 16 + (nn >> 6);
          int hd = nn & 63, srow = m & 2047;
          u16* o = (u16*)outp + proj * 4194304;
          if (proj < 2)
            o[(bh * 2048 + srow) * 64 + hd] = f2bf(v);
          else
            o[(bh * 64 + hd) * 2048 + srow] = f2bf(v);
        } else {
          ((float*)outp)[m * 1024 + n] = v + bias[n];
        }
      }
}

// ---------------- flash attention: 1 wave per block, swapped-operand 32x32 ----------
// Q,K: [BH=32][S=2048][64] bf16 (Q pre-scaled by 0.125*log2e); Vt: [BH][64][2048] bf16
// Ctx: [4096][1024] bf16. 2048 blocks; longest q-tiles launched first; head%8 = XCD.
__global__ __launch_bounds__(64) void attn_kernel(const u16* __restrict__ Q,
                                                  const u16* __restrict__ Kb,
                                                  const u16* __restrict__ Vt,
                                                  u16* __restrict__ Ctx) {
  __shared__ __align__(16) u16 tl[32 * 68];
  int l = threadIdx.x;
  int lq = l & 31, h = l >> 5;

  int B = blockIdx.x;
  int head = (B & 7) + 8 * ((B >> 3) & 3);  // head % 8 pinned to XCD
  int qt = 63 - (B >> 5);                   // longest first
  int q0 = qt * 32;

  const u16* Qp = Q + (head * 2048 + q0) * 64;
  const u16* Kp = Kb + head * 2048 * 64;
  const u16* Vp = Vt + head * 64 * 2048;

  // Q fragments (B-operand: Q^T[d][q], lane holds q=lq, d = f*16 + h*8 + j)
  s16x8 qf[4];
#pragma unroll
  for (int f = 0; f < 4; f++)
    qf[f] = *reinterpret_cast<const s16x8*>(Qp + lq * 64 + f * 16 + h * 8);

  f32x16 oacc[2];
#pragma unroll
  for (int dt = 0; dt < 2; dt++)
#pragma unroll
    for (int r = 0; r < 16; r++) oacc[dt][r] = 0.f;

  float mrun = -INFINITY, lrun = 0.f;
  int q = q0 + lq;
  int nt = qt + 1;

  // preload K tile 0 (A-operand: K[key][d])
  s16x8 kc[4];
#pragma unroll
  for (int f = 0; f < 4; f++)
    kc[f] = *reinterpret_cast<const s16x8*>(Kp + lq * 64 + f * 16 + h * 8);

  for (int kt = 0; kt < nt; kt++) {
    int kb = kt * 32;

    // V fragments for this tile (A-operand of PV: V^T[d][key])
    s16x8 vf[2][2];
#pragma unroll
    for (int dt = 0; dt < 2; dt++)
#pragma unroll
      for (int kh = 0; kh < 2; kh++)
        vf[dt][kh] = *reinterpret_cast<const s16x8*>(
            Vp + (dt * 32 + lq) * 2048 + kb + kh * 16 + h * 8);

    // S^T tile: rows=key (reg-mapped), col=q
    f32x16 s;
#pragma unroll
    for (int r = 0; r < 16; r++) s[r] = 0.f;
    __builtin_amdgcn_s_setprio(1);
#pragma unroll
    for (int f = 0; f < 4; f++) s = MFMA32(kc[f], qf[f], s);
    __builtin_amdgcn_s_setprio(0);

    // prefetch next K tile (hides under softmax+PV)
    if (kt + 1 < nt) {
#pragma unroll
      for (int f = 0; f < 4; f++)
        kc[f] = *reinterpret_cast<const s16x8*>(
            Kp + (kb + 32 + lq) * 64 + f * 16 + h * 8);
    }

    float p[16];
    if (kb == q0) {  // diagonal tile: the only masked one
#pragma unroll
      for (int r = 0; r < 16; r++) {
        int key = kb + (r & 3) + 8 * (r >> 2) + 4 * h;
        p[r] = (key <= q) ? s[r] : -INFINITY;
      }
    } else {
#pragma unroll
      for (int r = 0; r < 16; r++) p[r] = s[r];
    }

    // in-register softmax (log2 domain; scale folded into wq)
    float tm = p[0];
#pragma unroll
    for (int r = 1; r < 16; r++) tm = fmaxf(tm, p[r]);
    tm = fmaxf(tm, __shfl_xor(tm, 32));
    // defer-max (T13): skip O/l rescale while max growth <= 8 (P bounded by 2^8)
    if (!__all(tm - mrun <= 8.0f)) {
      float mnew = fmaxf(mrun, tm);
      float alpha = exp2f(mrun - mnew);
      lrun *= alpha;
#pragma unroll
      for (int r = 0; r < 16; r++) { oacc[0][r] *= alpha; oacc[1][r] *= alpha; }
      mrun = mnew;
    }
    float sum = 0.f;
#pragma unroll
    for (int r = 0; r < 16; r++) {
      p[r] = exp2f(p[r] - mrun);
      sum += p[r];
    }
    sum += __shfl_xor(sum, 32);
    lrun += sum;

    // pack P^T to bf16 B-fragments via shfl_xor(32) exchange.
    u32 pw[2][4];
#pragma unroll
    for (int kh = 0; kh < 2; kh++) {
      u32 w0 = pack2bf(p[kh * 8 + 0], p[kh * 8 + 1]);
      u32 w1 = pack2bf(p[kh * 8 + 2], p[kh * 8 + 3]);
      u32 w2 = pack2bf(p[kh * 8 + 4], p[kh * 8 + 5]);
      u32 w3 = pack2bf(p[kh * 8 + 6], p[kh * 8 + 7]);
      u32 y0 = sx32(w0);
      u32 y1 = sx32(w1);
      u32 y2 = sx32(w2);
      u32 y3 = sx32(w3);
      pw[kh][0] = h ? y2 : w0;  // j=0,1
      pw[kh][1] = h ? y3 : w1;  // j=2,3
      pw[kh][2] = h ? w2 : y0;  // j=4,5
      pw[kh][3] = h ? w3 : y1;  // j=6,7
    }

    // O^T += V^T @ P^T
    __builtin_amdgcn_s_setprio(1);
#pragma unroll
    for (int kh = 0; kh < 2; kh++) {
      s16x8 pf = __builtin_bit_cast(s16x8, u32x4{pw[kh][0], pw[kh][1], pw[kh][2], pw[kh][3]});
      oacc[0] = MFMA32(vf[0][kh], pf, oacc[0]);
      oacc[1] = MFMA32(vf[1][kh], pf, oacc[1]);
    }
    __builtin_amdgcn_s_setprio(0);
  }

  // epilogue: normalize, transpose O^T[d][q] -> [q][d] through LDS, coalesced store
  float invl = 1.0f / lrun;
#pragma unroll
  for (int dt = 0; dt < 2; dt++)
#pragma unroll
    for (int i = 0; i < 8; i++) {
      int d = ((2 * i) & 3) + 8 * (i >> 1) + 4 * h + dt * 32;
      u32 pkv = pack2bf(oacc[dt][2 * i] * invl, oacc[dt][2 * i + 1] * invl);
      *reinterpret_cast<u32*>(tl + lq * 68 + d) = pkv;
    }

  int b = head >> 4, hh = head & 15;
  int gbase = b * 2048 + q0;
#pragma unroll
  for (int i = 0; i < 8; i++) {
    int chunk = i * 64 + l;
    int row = chunk >> 4, col4 = (chunk & 15) * 4;
    u32x2 v = *reinterpret_cast<const u32x2*>(tl + row * 68 + col4);
    *reinterpret_cast<u32x2*>(Ctx + (gbase + row) * 1024 + hh * 64 + col4) = v;
  }
}

extern "C" void kernel_launch(void* const* d_in, const int* in_sizes, int n_in,
                              void* d_out, int out_size, void* d_ws, size_t ws_size,
                              hipStream_t stream) {
  const float* x = (const float*)d_in[0];
  const float* wq = (const float*)d_in[1];
  const float* wk = (const float*)d_in[2];
  const float* wv = (const float*)d_in[3];
  const float* wo = (const float*)d_in[4];
  const float* bo = (const float*)d_in[5];

  char* ws = (char*)d_ws;
  const size_t MB = 1 << 20;
  u16* xb    = (u16*)(ws + 0 * MB);    // 8 MB : x bf16 [4096][1024]
  u16* wqkvt = (u16*)(ws + 8 * MB);    // 6 MB : [wq^T;wk^T;wv^T] bf16 [3072][1024]
  u16* wot   = (u16*)(ws + 14 * MB);   // 2 MB : wo^T bf16
  u16* qkv   = (u16*)(ws + 16 * MB);   // 24 MB: qb @16, kb @24, vtb @32 (each 8 MB)
  u16* ctx   = (u16*)(ws + 40 * MB);   // 8 MB : ctx [4096][1024]

  const float QSCALE = 0.125f * 1.44269504f;  // 1/sqrt(64) * log2(e)

  cvt_bf16<<<4096, 256, 0, stream>>>(x, xb, 1048576);
  transp4<<<dim3(16, 16, 4), 256, 0, stream>>>(wq, wk, wv, wo, wqkvt, wot, QSCALE);

  gemm2<0><<<dim3(24, 32), 256, 0, stream>>>(xb, wqkvt, nullptr, qkv);

  attn_kernel<<<2048, 64, 0, stream>>>(qkv, qkv + 4194304, qkv + 8388608, ctx);

  gemm2<1><<<dim3(8, 32), 256, 0, stream>>>(ctx, wot, bo, d_out);
}

// Round 6
// 148.715 us; speedup vs baseline: 1.8732x; 1.0722x over previous
//
#include <hip/hip_runtime.h>

typedef short s16x8 __attribute__((ext_vector_type(8)));
typedef float f32x4 __attribute__((ext_vector_type(4)));
typedef float f32x16 __attribute__((ext_vector_type(16)));
typedef unsigned int u32;
typedef u32 u32x2 __attribute__((ext_vector_type(2)));
typedef u32 u32x4 __attribute__((ext_vector_type(4)));
typedef unsigned short u16;

#define MFMA16(a, b, c) __builtin_amdgcn_mfma_f32_16x16x32_bf16((a), (b), (c), 0, 0, 0)
#define MFMA32(a, b, c) __builtin_amdgcn_mfma_f32_32x32x16_bf16((a), (b), (c), 0, 0, 0)

__device__ __forceinline__ u16 f2bf(float f) {
  unsigned u = __builtin_bit_cast(unsigned, f);
  unsigned r = (u + 0x7FFFu + ((u >> 16) & 1u)) >> 16;
  return (u16)r;
}

__device__ __forceinline__ u32 pack2bf(float lo, float hi) {
  return (u32)f2bf(lo) | ((u32)f2bf(hi) << 16);
}

__device__ __forceinline__ float bf2f(u32 lo16) {
  return __builtin_bit_cast(float, lo16 << 16);
}

__device__ __forceinline__ u32 sx32(u32 v) {
  return (u32)__shfl_xor((int)v, 32);
}

// async global->LDS, 16B per lane. LDS dest must be wave-uniform base (HW adds lane*16).
__device__ __forceinline__ void gl_lds16(const u16* g, u16* s) {
  __builtin_amdgcn_global_load_lds(
      (const __attribute__((address_space(1))) void*)g,
      (__attribute__((address_space(3))) void*)s, 16, 0, 0);
}

// ---------------- fp32 -> bf16 elementwise (x) ----------------
__global__ __launch_bounds__(256) void cvt_bf16(const float* __restrict__ in,
                                                u16* __restrict__ out, int n4) {
  int i = blockIdx.x * 256 + threadIdx.x;
  if (i < n4) {
    float4 v = reinterpret_cast<const float4*>(in)[i];
    ushort4 o;
    o.x = f2bf(v.x); o.y = f2bf(v.y); o.z = f2bf(v.z); o.w = f2bf(v.w);
    reinterpret_cast<ushort4*>(out)[i] = o;
  }
}

// ---------------- all 4 weights: fp32 [1024][1024] -> bf16 transpose (one kernel) ----
__global__ __launch_bounds__(256) void transp4(const float* __restrict__ wq,
                                               const float* __restrict__ wk,
                                               const float* __restrict__ wv,
                                               const float* __restrict__ wo,
                                               u16* __restrict__ wqkvt,
                                               u16* __restrict__ wot, float qscale) {
  __shared__ float tile[64][65];
  int z = blockIdx.z;
  const float* W = (z == 0) ? wq : (z == 1) ? wk : (z == 2) ? wv : wo;
  u16* out = (z < 3) ? (wqkvt + z * 1048576) : wot;
  float sc = (z == 0) ? qscale : 1.0f;
  int n0 = blockIdx.x * 64, k0 = blockIdx.y * 64;
  int t = threadIdx.x;
#pragma unroll
  for (int i = 0; i < 16; i++) {
    int idx = t + i * 256;
    int r = idx >> 6, c = idx & 63;
    tile[r][c] = W[(k0 + r) * 1024 + (n0 + c)];
  }
  __syncthreads();
#pragma unroll
  for (int i = 0; i < 16; i++) {
    int idx = t + i * 256;
    int r = idx >> 6, c = idx & 63;
    out[(n0 + r) * 1024 + (k0 + c)] = f2bf(tile[c][r] * sc);
  }
}

// ---------------- 2-phase global_load_lds GEMM: C = A[M][1024] @ Bt[N][1024]^T ------
// MODE 0: fused QKV epilogue. outp = base of {qb, kb, vtb} (each 4M u16).
// MODE 1: fp32 out [M][1024] = acc + bias[n]
template <int MODE>
__global__ __launch_bounds__(256) void gemm2(const u16* __restrict__ A,
                                             const u16* __restrict__ Bt,
                                             const float* __restrict__ bias,
                                             void* __restrict__ outp) {
  constexpr int K = 1024, NT = K / 32;
  __shared__ __align__(16) u16 As[2][128 * 32];
  __shared__ __align__(16) u16 Bs[2][128 * 32];
  int t = threadIdx.x, w = t >> 6, l = t & 63;
  int m0 = blockIdx.y * 128, n0 = blockIdx.x * 128;
  int wm = (w >> 1) * 64, wn = (w & 1) * 64;
  int g = l >> 4, ql = l & 15;

  f32x4 acc[4][4];
#pragma unroll
  for (int i = 0; i < 4; i++)
#pragma unroll
    for (int j = 0; j < 4; j++) acc[i][j] = f32x4{0.f, 0.f, 0.f, 0.f};

  int lrow = l >> 2, lcol = (l & 3) * 8;
  const u16* Ag0 = A + (m0 + 32 * w + lrow) * K + lcol;
  const u16* Bg0 = Bt + (n0 + 32 * w + lrow) * K + lcol;
  u16* Asw[2] = {&As[0][(32 * w) * 32], &As[1][(32 * w) * 32]};
  u16* Bsw[2] = {&Bs[0][(32 * w) * 32], &Bs[1][(32 * w) * 32]};

#define STAGE(buf, kt)                              \
  do {                                              \
    int k0_ = (kt) * 32;                            \
    gl_lds16(Ag0 + k0_, Asw[buf]);                  \
    gl_lds16(Ag0 + 16 * K + k0_, Asw[buf] + 512);   \
    gl_lds16(Bg0 + k0_, Bsw[buf]);                  \
    gl_lds16(Bg0 + 16 * K + k0_, Bsw[buf] + 512);   \
  } while (0)

#define COMPUTE(buf)                                                              \
  do {                                                                            \
    s16x8 af[4], bv[4];                                                           \
    _Pragma("unroll") for (int fm = 0; fm < 4; fm++)                              \
        af[fm] = *reinterpret_cast<const s16x8*>(                                 \
            &As[buf][(wm + fm * 16 + ql) * 32 + g * 8]);                          \
    _Pragma("unroll") for (int fn = 0; fn < 4; fn++)                              \
        bv[fn] = *reinterpret_cast<const s16x8*>(                                 \
            &Bs[buf][(wn + fn * 16 + ql) * 32 + g * 8]);                          \
    _Pragma("unroll") for (int fm = 0; fm < 4; fm++)                              \
        _Pragma("unroll") for (int fn = 0; fn < 4; fn++)                          \
            acc[fm][fn] = MFMA16(af[fm], bv[fn], acc[fm][fn]);                    \
  } while (0)

  STAGE(0, 0);
  __syncthreads();
  int cur = 0;
  for (int kt = 0; kt < NT - 1; kt++) {
    STAGE(cur ^ 1, kt + 1);
    COMPUTE(cur);
    __syncthreads();
    cur ^= 1;
  }
  COMPUTE(cur);
#undef STAGE
#undef COMPUTE

#pragma unroll
  for (int fm = 0; fm < 4; fm++)
#pragma unroll
    for (int fn = 0; fn < 4; fn++)
#pragma unroll
      for (int j = 0; j < 4; j++) {
        int m = m0 + wm + fm * 16 + g * 4 + j;
        int n = n0 + wn + fn * 16 + ql;
        float v = acc[fm][fn][j];
        if (MODE == 0) {
          int proj = n >> 10, nn = n & 1023;
          int bh = (m >> 11) * 16 + (nn >> 6);
          int hd = nn & 63, srow = m & 2047;
          u16* o = (u16*)outp + proj * 4194304;
          if (proj < 2)
            o[(bh * 2048 + srow) * 64 + hd] = f2bf(v);
          else
            o[(bh * 64 + hd) * 2048 + srow] = f2bf(v);
        } else {
          ((float*)outp)[m * 1024 + n] = v + bias[n];
        }
      }
}

// ---------------- flash attention, split-K over the causal triangle ----------------
// Q,K: [BH=32][S=2048][64] bf16 (Q pre-scaled by 0.125*log2e); Vt: [BH][64][2048] bf16
// 3072 blocks x 64 threads. r = B>>5:
//   r in [ 0,32): qt=63-r, tiles [0,32)      -> partial chunk 0   (32 tiles)
//   r in [32,64): qt=95-r, tiles [32,qt+1)   -> partial chunk 1   (1..32 tiles)
//   r in [64,96): qt=95-r, tiles [0,qt+1)    -> full, write Ctx   (1..32 tiles)
// Partial record idx=(head*32+qt-32)*2+chunk: O^T raw bf16 (lane*32 u16) + per-lane m,l.
__global__ __launch_bounds__(64) void attn_kernel(const u16* __restrict__ Q,
                                                  const u16* __restrict__ Kb,
                                                  const u16* __restrict__ Vt,
                                                  u16* __restrict__ Ctx,
                                                  u16* __restrict__ part_o,
                                                  float* __restrict__ part_ml) {
  __shared__ __align__(16) u16 tl[32 * 68];
  int l = threadIdx.x;
  int lq = l & 31, h = l >> 5;

  int B = blockIdx.x;
  int head = (B & 7) + 8 * ((B >> 3) & 3);  // head % 8 pinned to XCD
  int r = B >> 5;
  int qt, t0, t1, chunk;
  bool split;
  if (r < 32)      { qt = 63 - r; t0 = 0;  t1 = 32;     split = true;  chunk = 0; }
  else if (r < 64) { qt = 95 - r; t0 = 32; t1 = qt + 1; split = true;  chunk = 1; }
  else             { qt = 95 - r; t0 = 0;  t1 = qt + 1; split = false; chunk = 0; }
  int q0 = qt * 32;

  const u16* Qp = Q + (head * 2048 + q0) * 64;
  const u16* Kp = Kb + head * 2048 * 64;
  const u16* Vp = Vt + head * 64 * 2048;

  // Q fragments (B-operand: Q^T[d][q], lane holds q=lq, d = f*16 + h*8 + j)
  s16x8 qf[4];
#pragma unroll
  for (int f = 0; f < 4; f++)
    qf[f] = *reinterpret_cast<const s16x8*>(Qp + lq * 64 + f * 16 + h * 8);

  f32x16 oacc[2];
#pragma unroll
  for (int dt = 0; dt < 2; dt++)
#pragma unroll
    for (int rr = 0; rr < 16; rr++) oacc[dt][rr] = 0.f;

  float mrun = -INFINITY, lrun = 0.f;
  int q = q0 + lq;

  // preload K tile t0 (A-operand: K[key][d])
  s16x8 kc[4];
#pragma unroll
  for (int f = 0; f < 4; f++)
    kc[f] = *reinterpret_cast<const s16x8*>(Kp + (t0 * 32 + lq) * 64 + f * 16 + h * 8);

  for (int kt = t0; kt < t1; kt++) {
    int kb = kt * 32;

    // V fragments for this tile (A-operand of PV: V^T[d][key])
    s16x8 vf[2][2];
#pragma unroll
    for (int dt = 0; dt < 2; dt++)
#pragma unroll
      for (int kh = 0; kh < 2; kh++)
        vf[dt][kh] = *reinterpret_cast<const s16x8*>(
            Vp + (dt * 32 + lq) * 2048 + kb + kh * 16 + h * 8);

    // S^T tile: rows=key (reg-mapped), col=q
    f32x16 s;
#pragma unroll
    for (int rr = 0; rr < 16; rr++) s[rr] = 0.f;
    __builtin_amdgcn_s_setprio(1);
#pragma unroll
    for (int f = 0; f < 4; f++) s = MFMA32(kc[f], qf[f], s);
    __builtin_amdgcn_s_setprio(0);

    // prefetch next K tile (hides under softmax+PV)
    if (kt + 1 < t1) {
#pragma unroll
      for (int f = 0; f < 4; f++)
        kc[f] = *reinterpret_cast<const s16x8*>(
            Kp + (kb + 32 + lq) * 64 + f * 16 + h * 8);
    }

    float p[16];
    if (kb == q0) {  // diagonal tile (only in full / upper-chunk last tile)
#pragma unroll
      for (int rr = 0; rr < 16; rr++) {
        int key = kb + (rr & 3) + 8 * (rr >> 2) + 4 * h;
        p[rr] = (key <= q) ? s[rr] : -INFINITY;
      }
    } else {
#pragma unroll
      for (int rr = 0; rr < 16; rr++) p[rr] = s[rr];
    }

    // in-register softmax (log2 domain; scale folded into wq)
    float tm = p[0];
#pragma unroll
    for (int rr = 1; rr < 16; rr++) tm = fmaxf(tm, p[rr]);
    tm = fmaxf(tm, __shfl_xor(tm, 32));
    // defer-max (T13): skip O/l rescale while max growth <= 8 (P bounded by 2^8)
    if (!__all(tm - mrun <= 8.0f)) {
      float mnew = fmaxf(mrun, tm);
      float alpha = exp2f(mrun - mnew);
      lrun *= alpha;
#pragma unroll
      for (int rr = 0; rr < 16; rr++) { oacc[0][rr] *= alpha; oacc[1][rr] *= alpha; }
      mrun = mnew;
    }
    float sum = 0.f;
#pragma unroll
    for (int rr = 0; rr < 16; rr++) {
      p[rr] = exp2f(p[rr] - mrun);
      sum += p[rr];
    }
    sum += __shfl_xor(sum, 32);
    lrun += sum;

    // pack P^T to bf16 B-fragments via shfl_xor(32) exchange.
    u32 pw[2][4];
#pragma unroll
    for (int kh = 0; kh < 2; kh++) {
      u32 w0 = pack2bf(p[kh * 8 + 0], p[kh * 8 + 1]);
      u32 w1 = pack2bf(p[kh * 8 + 2], p[kh * 8 + 3]);
      u32 w2 = pack2bf(p[kh * 8 + 4], p[kh * 8 + 5]);
      u32 w3 = pack2bf(p[kh * 8 + 6], p[kh * 8 + 7]);
      u32 y0 = sx32(w0);
      u32 y1 = sx32(w1);
      u32 y2 = sx32(w2);
      u32 y3 = sx32(w3);
      pw[kh][0] = h ? y2 : w0;  // j=0,1
      pw[kh][1] = h ? y3 : w1;  // j=2,3
      pw[kh][2] = h ? w2 : y0;  // j=4,5
      pw[kh][3] = h ? w3 : y1;  // j=6,7
    }

    // O^T += V^T @ P^T
    __builtin_amdgcn_s_setprio(1);
#pragma unroll
    for (int kh = 0; kh < 2; kh++) {
      s16x8 pf = __builtin_bit_cast(s16x8, u32x4{pw[kh][0], pw[kh][1], pw[kh][2], pw[kh][3]});
      oacc[0] = MFMA32(vf[0][kh], pf, oacc[0]);
      oacc[1] = MFMA32(vf[1][kh], pf, oacc[1]);
    }
    __builtin_amdgcn_s_setprio(0);
  }

  if (split) {
    // store raw partial: 16 packed u32 per lane + (m, l)
    int idx = (head * 32 + (qt - 32)) * 2 + chunk;
    u32* po = reinterpret_cast<u32*>(part_o + (size_t)idx * 2048 + l * 32);
#pragma unroll
    for (int dt = 0; dt < 2; dt++)
#pragma unroll
      for (int i = 0; i < 8; i++)
        po[dt * 8 + i] = pack2bf(oacc[dt][2 * i], oacc[dt][2 * i + 1]);
    float* pml = part_ml + ((size_t)idx * 64 + l) * 2;
    pml[0] = mrun;
    pml[1] = lrun;
    return;
  }

  // full path: normalize, transpose O^T[d][q] -> [q][d] through LDS, coalesced store
  float invl = 1.0f / lrun;
#pragma unroll
  for (int dt = 0; dt < 2; dt++)
#pragma unroll
    for (int i = 0; i < 8; i++) {
      int d = ((2 * i) & 3) + 8 * (i >> 1) + 4 * h + dt * 32;
      u32 pkv = pack2bf(oacc[dt][2 * i] * invl, oacc[dt][2 * i + 1] * invl);
      *reinterpret_cast<u32*>(tl + lq * 68 + d) = pkv;
    }

  int b = head >> 4, hh = head & 15;
  int gbase = b * 2048 + q0;
#pragma unroll
  for (int i = 0; i < 8; i++) {
    int chunkk = i * 64 + l;
    int row = chunkk >> 4, col4 = (chunkk & 15) * 4;
    u32x2 v = *reinterpret_cast<const u32x2*>(tl + row * 68 + col4);
    *reinterpret_cast<u32x2*>(Ctx + (gbase + row) * 1024 + hh * 64 + col4) = v;
  }
}

// ---------------- combine two partials per split q-tile -> Ctx ----------------
__global__ __launch_bounds__(64) void attn_combine(const u16* __restrict__ part_o,
                                                   const float* __restrict__ part_ml,
                                                   u16* __restrict__ Ctx) {
  __shared__ __align__(16) u16 tl[32 * 68];
  int l = threadIdx.x, lq = l & 31, h = l >> 5;
  int B = blockIdx.x;              // 1024 = 32 heads x 32 split q-tiles
  int head = B & 31, qz = B >> 5;  // qt = 32 + qz
  int idx0 = (head * 32 + qz) * 2;

  const float* ml0 = part_ml + ((size_t)idx0 * 64 + l) * 2;
  const float* ml1 = part_ml + ((size_t)(idx0 + 1) * 64 + l) * 2;
  float m0 = ml0[0], l0 = ml0[1];
  float m1 = ml1[0], l1 = ml1[1];
  float m = fmaxf(m0, m1);
  float w0 = exp2f(m0 - m), w1 = exp2f(m1 - m);
  float invl = 1.0f / (l0 * w0 + l1 * w1);
  w0 *= invl; w1 *= invl;

  const u32* p0 = reinterpret_cast<const u32*>(part_o + (size_t)idx0 * 2048 + l * 32);
  const u32* p1 = reinterpret_cast<const u32*>(part_o + (size_t)(idx0 + 1) * 2048 + l * 32);
#pragma unroll
  for (int k = 0; k < 16; k++) {
    u32 a = p0[k], b = p1[k];
    float o0 = bf2f(a & 0xFFFFu) * w0 + bf2f(b & 0xFFFFu) * w1;
    float o1 = bf2f(a >> 16) * w0 + bf2f(b >> 16) * w1;
    int dt = k >> 3, i = k & 7;
    int d = ((2 * i) & 3) + 8 * (i >> 1) + 4 * h + dt * 32;
    *reinterpret_cast<u32*>(tl + lq * 68 + d) = pack2bf(o0, o1);
  }

  int b_ = head >> 4, hh = head & 15;
  int gbase = b_ * 2048 + (32 + qz) * 32;
#pragma unroll
  for (int i = 0; i < 8; i++) {
    int chunkk = i * 64 + l;
    int row = chunkk >> 4, col4 = (chunkk & 15) * 4;
    u32x2 v = *reinterpret_cast<const u32x2*>(tl + row * 68 + col4);
    *reinterpret_cast<u32x2*>(Ctx + (gbase + row) * 1024 + hh * 64 + col4) = v;
  }
}

extern "C" void kernel_launch(void* const* d_in, const int* in_sizes, int n_in,
                              void* d_out, int out_size, void* d_ws, size_t ws_size,
                              hipStream_t stream) {
  const float* x = (const float*)d_in[0];
  const float* wq = (const float*)d_in[1];
  const float* wk = (const float*)d_in[2];
  const float* wv = (const float*)d_in[3];
  const float* wo = (const float*)d_in[4];
  const float* bo = (const float*)d_in[5];

  char* ws = (char*)d_ws;
  const size_t MB = 1 << 20;
  u16* xb    = (u16*)(ws + 0 * MB);    // 8 MB : x bf16 (dead after QKV GEMM)
  u16* wqkvt = (u16*)(ws + 8 * MB);    // 6 MB : [wq^T;wk^T;wv^T] (dead after QKV GEMM)
  u16* wot   = (u16*)(ws + 14 * MB);   // 2 MB : wo^T (live until final GEMM)
  u16* qkv   = (u16*)(ws + 16 * MB);   // 24 MB: qb @16, kb @24, vtb @32
  u16* ctx   = (u16*)(ws + 40 * MB);   // 8 MB : ctx [4096][1024]
  // attention partials alias the dead xb/wqkvt region:
  u16* part_o  = (u16*)(ws + 0 * MB);  // 8 MB : 2048 records x 2048 u16
  float* part_ml = (float*)(ws + 8 * MB);  // 1 MB : 2048 records x 64 x {m,l}

  const float QSCALE = 0.125f * 1.44269504f;  // 1/sqrt(64) * log2(e)

  cvt_bf16<<<4096, 256, 0, stream>>>(x, xb, 1048576);
  transp4<<<dim3(16, 16, 4), 256, 0, stream>>>(wq, wk, wv, wo, wqkvt, wot, QSCALE);

  gemm2<0><<<dim3(24, 32), 256, 0, stream>>>(xb, wqkvt, nullptr, qkv);

  attn_kernel<<<3072, 64, 0, stream>>>(qkv, qkv + 4194304, qkv + 8388608, ctx,
                                       part_o, part_ml);
  attn_combine<<<1024, 64, 0, stream>>>(part_o, part_ml, ctx);

  gemm2<1><<<dim3(8, 32), 256, 0, stream>>>(ctx, wot, bo, d_out);
}